// Round 3
// baseline (2049.328 us; speedup 1.0000x reference)
//
#include <hip/hip_runtime.h>

#define N_NODES 100000
#define N_EDGES 1600000

// ================= CSR build =================
__global__ __launch_bounds__(256) void k_hist(const int* __restrict__ dst, int* __restrict__ deg) {
    int e = blockIdx.x * 256 + threadIdx.x;
    if (e < N_EDGES) atomicAdd(&deg[dst[e]], 1);
}

// block-level exclusive scan; writes per-element intra-block exclusive prefix to rowstart, block sums to bsum
__global__ __launch_bounds__(1024) void k_part_scan(const int* __restrict__ deg,
                                                    int* __restrict__ rowstart, int* __restrict__ bsum) {
    __shared__ int wsum[16];
    const int tid = threadIdx.x, lane = tid & 63, wid = tid >> 6;
    int i = blockIdx.x * 1024 + tid;
    int v = (i < N_NODES) ? deg[i] : 0;
    int s = v;
    #pragma unroll
    for (int off = 1; off < 64; off <<= 1) {
        int t = __shfl_up(s, off);
        if (lane >= off) s += t;
    }
    if (lane == 63) wsum[wid] = s;
    __syncthreads();
    if (tid < 16) {
        int w = wsum[tid];
        #pragma unroll
        for (int off = 1; off < 16; off <<= 1) {
            int t = __shfl_up(w, off);
            if (tid >= off) w += t;
        }
        wsum[tid] = w;
    }
    __syncthreads();
    int wexcl = (wid == 0) ? 0 : wsum[wid - 1];
    if (i < N_NODES) rowstart[i] = wexcl + s - v;
    if (tid == 1023) bsum[blockIdx.x] = wexcl + s;
}

// scan the 98 block sums (one small block), also writes rowstart[N]
__global__ __launch_bounds__(128) void k_scan_bsum(const int* __restrict__ bsum, int* __restrict__ boff,
                                                   int* __restrict__ rowstart, int nblk) {
    __shared__ int sh[128];
    int t = threadIdx.x;
    int v = (t < nblk) ? bsum[t] : 0;
    int acc = v;
    sh[t] = acc;
    __syncthreads();
    #pragma unroll
    for (int off = 1; off < 128; off <<= 1) {
        int add = (t >= off) ? sh[t - off] : 0;
        __syncthreads();
        acc += add;
        sh[t] = acc;
        __syncthreads();
    }
    if (t < nblk) boff[t] = acc - v;
    if (t == nblk - 1) rowstart[N_NODES] = acc;
}

__global__ __launch_bounds__(1024) void k_add_off(const int* __restrict__ boff, int* __restrict__ rowstart) {
    int i = blockIdx.x * 1024 + threadIdx.x;
    if (i < N_NODES) rowstart[i] += boff[blockIdx.x];
}

__global__ __launch_bounds__(256) void k_fill(const int* __restrict__ src, const int* __restrict__ dst,
                                             int* __restrict__ cursor, int* __restrict__ srcs_sorted) {
    int e = blockIdx.x * 256 + threadIdx.x;
    if (e < N_EDGES) {
        int d = dst[e];
        int p = atomicAdd(&cursor[d], 1);
        srcs_sorted[p] = src[e];
    }
}

// ================= layer 1: edge-parallel gather (LDS atomics) + dense + relu =================
__global__ __launch_bounds__(256) void k_layer1(
    const float* __restrict__ x, const int* __restrict__ rowstart, const int* __restrict__ srcs,
    const float* __restrict__ Wl, const float* __restrict__ Wr, const float* __restrict__ b,
    float* __restrict__ h1)
{
    __shared__ float la[32][68];
    __shared__ float lx[32][68];
    __shared__ int rs[33];
    const int tile = blockIdx.x * 32;          // 100000 = 3125*32
    const int tid = threadIdx.x, lane = tid & 63, wid = tid >> 6;

    if (tid < 33) rs[tid] = rowstart[tile + tid];
    #pragma unroll
    for (int r = 0; r < 8; ++r) {
        int flat = r * 256 + tid;
        int node = flat >> 6, k = flat & 63;
        lx[node][k] = x[(size_t)(tile + node) * 64 + k];
        la[node][k] = 0.0f;
    }
    __syncthreads();

    const int E0 = rs[0], E1 = rs[32];
    // each wave takes 4 consecutive edges, strided across 4 waves
    for (int eb = E0 + wid * 4; eb < E1; eb += 16) {
        #pragma unroll
        for (int j = 0; j < 4; ++j) {
            int e = eb + j;
            if (e < E1) {
                int s = srcs[e];
                float v = x[(size_t)s * 64 + lane];
                int lo = 0;                      // node bucket: max lo with rs[lo] <= e
                #pragma unroll
                for (int st = 16; st > 0; st >>= 1)
                    if (e >= rs[lo + st]) lo += st;
                unsafeAtomicAdd(&la[lo][lane], v);
            }
        }
    }
    __syncthreads();

    // scale by 1/deg
    #pragma unroll
    for (int r = 0; r < 8; ++r) {
        int flat = r * 256 + tid;
        int node = flat >> 6, k = flat & 63;
        int d = rs[node + 1] - rs[node];
        la[node][k] *= (d > 0) ? (1.0f / (float)d) : 1.0f;
    }
    __syncthreads();

    const int jg = tid & 31, ng = tid >> 5;
    const int j4 = jg * 4, nb = ng * 4;
    float acc[4][4] = {};
    for (int k = 0; k < 64; ++k) {
        float4 w1 = *reinterpret_cast<const float4*>(Wl + k * 128 + j4);
        float4 w2 = *reinterpret_cast<const float4*>(Wr + k * 128 + j4);
        #pragma unroll
        for (int i = 0; i < 4; ++i) {
            float a = la[nb + i][k], xx = lx[nb + i][k];
            acc[i][0] += a * w1.x + xx * w2.x;
            acc[i][1] += a * w1.y + xx * w2.y;
            acc[i][2] += a * w1.z + xx * w2.z;
            acc[i][3] += a * w1.w + xx * w2.w;
        }
    }
    float4 bb = *reinterpret_cast<const float4*>(b + j4);
    #pragma unroll
    for (int i = 0; i < 4; ++i) {
        int n = tile + nb + i;
        float4 o;
        o.x = fmaxf(acc[i][0] + bb.x, 0.0f);
        o.y = fmaxf(acc[i][1] + bb.y, 0.0f);
        o.z = fmaxf(acc[i][2] + bb.z, 0.0f);
        o.w = fmaxf(acc[i][3] + bb.w, 0.0f);
        *reinterpret_cast<float4*>(h1 + (size_t)n * 128 + j4) = o;
    }
}

// ================= layer 2 + heads: edge-parallel gather + dense + relu + heads =================
__global__ __launch_bounds__(256) void k_layer2(
    const float* __restrict__ h1, const int* __restrict__ rowstart, const int* __restrict__ srcs,
    const float* __restrict__ Wl, const float* __restrict__ Wr, const float* __restrict__ b,
    const float* __restrict__ Wh, const float* __restrict__ bh,
    const float* __restrict__ Wm, const float* __restrict__ bm,
    float* __restrict__ out1, float* __restrict__ out2)
{
    __shared__ float la[32][132];
    __shared__ float lh[32][132];
    __shared__ int rs[33];
    const int tile = blockIdx.x * 32;
    const int tid = threadIdx.x, lane = tid & 63, wid = tid >> 6;

    if (tid < 33) rs[tid] = rowstart[tile + tid];
    #pragma unroll
    for (int r = 0; r < 16; ++r) {
        int flat = r * 256 + tid;
        int node = flat >> 7, k = flat & 127;
        lh[node][k] = h1[(size_t)(tile + node) * 128 + k];
        la[node][k] = 0.0f;
    }
    __syncthreads();

    const int E0 = rs[0], E1 = rs[32];
    for (int eb = E0 + wid * 4; eb < E1; eb += 16) {
        #pragma unroll
        for (int j = 0; j < 4; ++j) {
            int e = eb + j;
            if (e < E1) {
                int s = srcs[e];
                float2 v = *reinterpret_cast<const float2*>(h1 + (size_t)s * 128 + lane * 2);
                int lo = 0;
                #pragma unroll
                for (int st = 16; st > 0; st >>= 1)
                    if (e >= rs[lo + st]) lo += st;
                unsafeAtomicAdd(&la[lo][lane * 2], v.x);
                unsafeAtomicAdd(&la[lo][lane * 2 + 1], v.y);
            }
        }
    }
    __syncthreads();

    #pragma unroll
    for (int r = 0; r < 16; ++r) {
        int flat = r * 256 + tid;
        int node = flat >> 7, k = flat & 127;
        int d = rs[node + 1] - rs[node];
        la[node][k] *= (d > 0) ? (1.0f / (float)d) : 1.0f;
    }
    __syncthreads();

    const int jg = tid & 31, ng = tid >> 5;
    const int j4 = jg * 4, nb = ng * 4;
    float acc[4][4] = {};
    for (int k = 0; k < 128; ++k) {
        float4 w1 = *reinterpret_cast<const float4*>(Wl + k * 128 + j4);
        float4 w2 = *reinterpret_cast<const float4*>(Wr + k * 128 + j4);
        #pragma unroll
        for (int i = 0; i < 4; ++i) {
            float a = la[nb + i][k], hh = lh[nb + i][k];
            acc[i][0] += a * w1.x + hh * w2.x;
            acc[i][1] += a * w1.y + hh * w2.y;
            acc[i][2] += a * w1.z + hh * w2.z;
            acc[i][3] += a * w1.w + hh * w2.w;
        }
    }
    __syncthreads();   // done reading la/lh

    float4 bb = *reinterpret_cast<const float4*>(b + j4);
    #pragma unroll
    for (int i = 0; i < 4; ++i) {
        float4 o;
        o.x = fmaxf(acc[i][0] + bb.x, 0.0f);
        o.y = fmaxf(acc[i][1] + bb.y, 0.0f);
        o.z = fmaxf(acc[i][2] + bb.z, 0.0f);
        o.w = fmaxf(acc[i][3] + bb.w, 0.0f);
        *reinterpret_cast<float4*>(&la[nb + i][j4]) = o;   // h2 tile into LDS
    }
    __syncthreads();

    for (int t = tid; t < 352; t += 256) {
        int node = t / 11, o = t - node * 11;
        const float* h2 = &la[node][0];
        if (o < 3) {
            float s = bh[o];
            for (int k = 0; k < 128; ++k) s += h2[k] * Wh[k * 3 + o];
            out1[(size_t)(tile + node) * 3 + o] = s;
        } else {
            int m = o - 3;
            float s = bm[m];
            for (int k = 0; k < 128; ++k) s += h2[k] * Wm[k * 8 + m];
            out2[(size_t)(tile + node) * 8 + m] = s;
        }
    }
}

extern "C" void kernel_launch(void* const* d_in, const int* in_sizes, int n_in,
                              void* d_out, int out_size, void* d_ws, size_t ws_size,
                              hipStream_t stream) {
    const float* x   = (const float*)d_in[0];
    const int*   ei  = (const int*)d_in[1];
    const int*   src = ei;
    const int*   dst = ei + N_EDGES;
    const float* Wl1 = (const float*)d_in[2];
    const float* Wr1 = (const float*)d_in[3];
    const float* b1  = (const float*)d_in[4];
    const float* Wl2 = (const float*)d_in[5];
    const float* Wr2 = (const float*)d_in[6];
    const float* b2  = (const float*)d_in[7];
    const float* Wh  = (const float*)d_in[8];
    const float* bh  = (const float*)d_in[9];
    const float* Wm  = (const float*)d_in[10];
    const float* bm  = (const float*)d_in[11];

    float* out1 = (float*)d_out;                   // [N,3]
    float* out2 = out1 + (size_t)N_NODES * 3;      // [N,8]

    char* ws = (char*)d_ws;
    int*   deg      = (int*)(ws);                  // 100000 ints
    int*   rowstart = (int*)(ws + (512 << 10));    // 100001 ints
    int*   cursor   = (int*)(ws + (1024 << 10));   // 100000 ints
    int*   bsum     = (int*)(ws + (1408 << 10));   // 98 ints
    int*   boff     = (int*)(ws + (1472 << 10));   // 98 ints
    int*   srcs     = (int*)(ws + (1536 << 10));   // 1.6M ints (6.4 MB)
    float* h1       = (float*)(ws + (8192 << 10)); // 100000*128 floats (51.2 MB)

    const int NSCAN = (N_NODES + 1023) / 1024;     // 98

    hipMemsetAsync(deg, 0, N_NODES * sizeof(int), stream);
    k_hist<<<6250, 256, 0, stream>>>(dst, deg);
    k_part_scan<<<NSCAN, 1024, 0, stream>>>(deg, rowstart, bsum);
    k_scan_bsum<<<1, 128, 0, stream>>>(bsum, boff, rowstart, NSCAN);
    k_add_off<<<NSCAN, 1024, 0, stream>>>(boff, rowstart);
    hipMemcpyAsync(cursor, rowstart, N_NODES * sizeof(int), hipMemcpyDeviceToDevice, stream);
    k_fill<<<6250, 256, 0, stream>>>(src, dst, cursor, srcs);

    k_layer1<<<3125, 256, 0, stream>>>(x, rowstart, srcs, Wl1, Wr1, b1, h1);
    k_layer2<<<3125, 256, 0, stream>>>(h1, rowstart, srcs, Wl2, Wr2, b2, Wh, bh, Wm, bm, out1, out2);
}

// Round 5
// 605.278 us; speedup vs baseline: 3.3858x; 3.3858x over previous
//
#include <hip/hip_runtime.h>

#define N_NODES 100000
#define N_EDGES 1600000

__device__ __forceinline__ float bf2f(unsigned short u) {
    return __uint_as_float(((unsigned int)u) << 16);
}
__device__ __forceinline__ unsigned short f2bf(float f) {
    unsigned int u = __float_as_uint(f);
    unsigned int r = (u + 0x7fffu + ((u >> 16) & 1u)) >> 16;   // round-to-nearest-even
    return (unsigned short)r;
}

// ================= CSR build =================
__global__ __launch_bounds__(256) void k_hist(const int* __restrict__ dst, int* __restrict__ deg) {
    int e = blockIdx.x * 256 + threadIdx.x;
    if (e < N_EDGES) atomicAdd(&deg[dst[e]], 1);
}

__global__ __launch_bounds__(1024) void k_part_scan(const int* __restrict__ deg,
                                                    int* __restrict__ rowstart, int* __restrict__ bsum) {
    __shared__ int wsum[16];
    const int tid = threadIdx.x, lane = tid & 63, wid = tid >> 6;
    int i = blockIdx.x * 1024 + tid;
    int v = (i < N_NODES) ? deg[i] : 0;
    int s = v;
    #pragma unroll
    for (int off = 1; off < 64; off <<= 1) {
        int t = __shfl_up(s, off);
        if (lane >= off) s += t;
    }
    if (lane == 63) wsum[wid] = s;
    __syncthreads();
    if (tid < 16) {
        int w = wsum[tid];
        #pragma unroll
        for (int off = 1; off < 16; off <<= 1) {
            int t = __shfl_up(w, off);
            if (tid >= off) w += t;
        }
        wsum[tid] = w;
    }
    __syncthreads();
    int wexcl = (wid == 0) ? 0 : wsum[wid - 1];
    if (i < N_NODES) rowstart[i] = wexcl + s - v;
    if (tid == 1023) bsum[blockIdx.x] = wexcl + s;
}

__global__ __launch_bounds__(128) void k_scan_bsum(const int* __restrict__ bsum, int* __restrict__ boff,
                                                   int* __restrict__ rowstart, int nblk) {
    __shared__ int sh[128];
    int t = threadIdx.x;
    int v = (t < nblk) ? bsum[t] : 0;
    int acc = v;
    sh[t] = acc;
    __syncthreads();
    #pragma unroll
    for (int off = 1; off < 128; off <<= 1) {
        int add = (t >= off) ? sh[t - off] : 0;
        __syncthreads();
        acc += add;
        sh[t] = acc;
        __syncthreads();
    }
    if (t < nblk) boff[t] = acc - v;
    if (t == nblk - 1) rowstart[N_NODES] = acc;
}

__global__ __launch_bounds__(1024) void k_add_off(const int* __restrict__ boff, int* __restrict__ rowstart) {
    int i = blockIdx.x * 1024 + threadIdx.x;
    if (i < N_NODES) rowstart[i] += boff[blockIdx.x];
}

__global__ __launch_bounds__(256) void k_fill(const int* __restrict__ src, const int* __restrict__ dst,
                                             int* __restrict__ cursor, int* __restrict__ srcs_sorted) {
    int e = blockIdx.x * 256 + threadIdx.x;
    if (e < N_EDGES) {
        int d = dst[e];
        int p = atomicAdd(&cursor[d], 1);
        srcs_sorted[p] = src[e];
    }
}

// ================= cast x to bf16 (message copy) =================
__global__ __launch_bounds__(256) void k_cast_x(const float* __restrict__ x, unsigned short* __restrict__ xh) {
    int i = blockIdx.x * 256 + threadIdx.x;     // 1.6M threads, 4 elems each
    float4 v = *reinterpret_cast<const float4*>(x + (size_t)i * 4);
    ushort4 o;
    o.x = f2bf(v.x); o.y = f2bf(v.y); o.z = f2bf(v.z); o.w = f2bf(v.w);
    *reinterpret_cast<ushort4*>(xh + (size_t)i * 4) = o;
}

// ================= layer 1: gather(bf16, unroll-4) + dense + relu =================
__global__ __launch_bounds__(256) void k_layer1(
    const float* __restrict__ x, const unsigned short* __restrict__ xh,
    const int* __restrict__ rowstart, const int* __restrict__ srcs,
    const float* __restrict__ Wl, const float* __restrict__ Wr, const float* __restrict__ b,
    float* __restrict__ h1, unsigned short* __restrict__ h1h)
{
    __shared__ float la[32][68];
    __shared__ float lx[32][68];
    __shared__ int rs[33];
    const int tile = blockIdx.x * 32;          // 100000 = 3125*32
    const int tid = threadIdx.x, lane = tid & 63, wid = tid >> 6;

    if (tid < 33) rs[tid] = rowstart[tile + tid];
    #pragma unroll
    for (int r = 0; r < 8; ++r) {
        int flat = r * 256 + tid;
        int node = flat >> 6, k = flat & 63;
        lx[node][k] = x[(size_t)(tile + node) * 64 + k];
    }
    __syncthreads();

    for (int it = 0; it < 8; ++it) {
        int node = wid * 8 + it;
        int e0 = rs[node], e1 = rs[node + 1];
        float a0 = 0.f, a1 = 0.f, a2 = 0.f, a3 = 0.f;
        int e = e0;
        for (; e + 4 <= e1; e += 4) {
            int s0 = srcs[e], s1 = srcs[e + 1], s2 = srcs[e + 2], s3 = srcs[e + 3];
            a0 += bf2f(xh[(size_t)s0 * 64 + lane]);
            a1 += bf2f(xh[(size_t)s1 * 64 + lane]);
            a2 += bf2f(xh[(size_t)s2 * 64 + lane]);
            a3 += bf2f(xh[(size_t)s3 * 64 + lane]);
        }
        for (; e < e1; ++e)
            a0 += bf2f(xh[(size_t)srcs[e] * 64 + lane]);
        float acc = (a0 + a1) + (a2 + a3);
        int d = e1 - e0;
        la[node][lane] = acc * ((d > 0) ? (1.0f / (float)d) : 1.0f);
    }
    __syncthreads();

    const int jg = tid & 31, ng = tid >> 5;
    const int j4 = jg * 4, nb = ng * 4;
    float acc[4][4] = {};
    for (int k = 0; k < 64; ++k) {
        float4 w1 = *reinterpret_cast<const float4*>(Wl + k * 128 + j4);
        float4 w2 = *reinterpret_cast<const float4*>(Wr + k * 128 + j4);
        #pragma unroll
        for (int i = 0; i < 4; ++i) {
            float a = la[nb + i][k], xx = lx[nb + i][k];
            acc[i][0] += a * w1.x + xx * w2.x;
            acc[i][1] += a * w1.y + xx * w2.y;
            acc[i][2] += a * w1.z + xx * w2.z;
            acc[i][3] += a * w1.w + xx * w2.w;
        }
    }
    float4 bb = *reinterpret_cast<const float4*>(b + j4);
    #pragma unroll
    for (int i = 0; i < 4; ++i) {
        int n = tile + nb + i;
        float4 o;
        o.x = fmaxf(acc[i][0] + bb.x, 0.0f);
        o.y = fmaxf(acc[i][1] + bb.y, 0.0f);
        o.z = fmaxf(acc[i][2] + bb.z, 0.0f);
        o.w = fmaxf(acc[i][3] + bb.w, 0.0f);
        *reinterpret_cast<float4*>(h1 + (size_t)n * 128 + j4) = o;
        ushort4 oh;
        oh.x = f2bf(o.x); oh.y = f2bf(o.y); oh.z = f2bf(o.z); oh.w = f2bf(o.w);
        *reinterpret_cast<ushort4*>(h1h + (size_t)n * 128 + j4) = oh;
    }
}

// ================= layer 2 + heads: gather(bf16x2, unroll-4) + dense + relu + heads =================
__global__ __launch_bounds__(256) void k_layer2(
    const float* __restrict__ h1, const unsigned int* __restrict__ h1h32,
    const int* __restrict__ rowstart, const int* __restrict__ srcs,
    const float* __restrict__ Wl, const float* __restrict__ Wr, const float* __restrict__ b,
    const float* __restrict__ Wh, const float* __restrict__ bh,
    const float* __restrict__ Wm, const float* __restrict__ bm,
    float* __restrict__ out1, float* __restrict__ out2)
{
    __shared__ float la[32][132];
    __shared__ float lh[32][132];
    __shared__ int rs[33];
    const int tile = blockIdx.x * 32;
    const int tid = threadIdx.x, lane = tid & 63, wid = tid >> 6;

    if (tid < 33) rs[tid] = rowstart[tile + tid];
    #pragma unroll
    for (int r = 0; r < 16; ++r) {
        int flat = r * 256 + tid;
        int node = flat >> 7, k = flat & 127;
        lh[node][k] = h1[(size_t)(tile + node) * 128 + k];
    }
    __syncthreads();

    for (int it = 0; it < 8; ++it) {
        int node = wid * 8 + it;
        int e0 = rs[node], e1 = rs[node + 1];
        float ax0 = 0.f, ay0 = 0.f, ax1 = 0.f, ay1 = 0.f;
        float ax2 = 0.f, ay2 = 0.f, ax3 = 0.f, ay3 = 0.f;
        int e = e0;
        for (; e + 4 <= e1; e += 4) {
            int s0 = srcs[e], s1 = srcs[e + 1], s2 = srcs[e + 2], s3 = srcs[e + 3];
            unsigned int u0 = h1h32[(size_t)s0 * 64 + lane];
            unsigned int u1 = h1h32[(size_t)s1 * 64 + lane];
            unsigned int u2 = h1h32[(size_t)s2 * 64 + lane];
            unsigned int u3 = h1h32[(size_t)s3 * 64 + lane];
            ax0 += __uint_as_float(u0 << 16); ay0 += __uint_as_float(u0 & 0xffff0000u);
            ax1 += __uint_as_float(u1 << 16); ay1 += __uint_as_float(u1 & 0xffff0000u);
            ax2 += __uint_as_float(u2 << 16); ay2 += __uint_as_float(u2 & 0xffff0000u);
            ax3 += __uint_as_float(u3 << 16); ay3 += __uint_as_float(u3 & 0xffff0000u);
        }
        for (; e < e1; ++e) {
            unsigned int u0 = h1h32[(size_t)srcs[e] * 64 + lane];
            ax0 += __uint_as_float(u0 << 16); ay0 += __uint_as_float(u0 & 0xffff0000u);
        }
        float ax = (ax0 + ax1) + (ax2 + ax3);
        float ay = (ay0 + ay1) + (ay2 + ay3);
        int d = e1 - e0;
        float rd = (d > 0) ? (1.0f / (float)d) : 1.0f;
        la[node][lane * 2]     = ax * rd;
        la[node][lane * 2 + 1] = ay * rd;
    }
    __syncthreads();

    const int jg = tid & 31, ng = tid >> 5;
    const int j4 = jg * 4, nb = ng * 4;
    float acc[4][4] = {};
    for (int k = 0; k < 128; ++k) {
        float4 w1 = *reinterpret_cast<const float4*>(Wl + k * 128 + j4);
        float4 w2 = *reinterpret_cast<const float4*>(Wr + k * 128 + j4);
        #pragma unroll
        for (int i = 0; i < 4; ++i) {
            float a = la[nb + i][k], hh = lh[nb + i][k];
            acc[i][0] += a * w1.x + hh * w2.x;
            acc[i][1] += a * w1.y + hh * w2.y;
            acc[i][2] += a * w1.z + hh * w2.z;
            acc[i][3] += a * w1.w + hh * w2.w;
        }
    }
    __syncthreads();   // done reading la/lh

    float4 bb = *reinterpret_cast<const float4*>(b + j4);
    #pragma unroll
    for (int i = 0; i < 4; ++i) {
        float4 o;
        o.x = fmaxf(acc[i][0] + bb.x, 0.0f);
        o.y = fmaxf(acc[i][1] + bb.y, 0.0f);
        o.z = fmaxf(acc[i][2] + bb.z, 0.0f);
        o.w = fmaxf(acc[i][3] + bb.w, 0.0f);
        *reinterpret_cast<float4*>(&la[nb + i][j4]) = o;   // h2 tile into LDS
    }
    __syncthreads();

    for (int t = tid; t < 352; t += 256) {
        int node = t / 11, o = t - node * 11;
        const float* h2 = &la[node][0];
        if (o < 3) {
            float s = bh[o];
            for (int k = 0; k < 128; ++k) s += h2[k] * Wh[k * 3 + o];
            out1[(size_t)(tile + node) * 3 + o] = s;
        } else {
            int m = o - 3;
            float s = bm[m];
            for (int k = 0; k < 128; ++k) s += h2[k] * Wm[k * 8 + m];
            out2[(size_t)(tile + node) * 8 + m] = s;
        }
    }
}

extern "C" void kernel_launch(void* const* d_in, const int* in_sizes, int n_in,
                              void* d_out, int out_size, void* d_ws, size_t ws_size,
                              hipStream_t stream) {
    const float* x   = (const float*)d_in[0];
    const int*   ei  = (const int*)d_in[1];
    const int*   src = ei;
    const int*   dst = ei + N_EDGES;
    const float* Wl1 = (const float*)d_in[2];
    const float* Wr1 = (const float*)d_in[3];
    const float* b1  = (const float*)d_in[4];
    const float* Wl2 = (const float*)d_in[5];
    const float* Wr2 = (const float*)d_in[6];
    const float* b2  = (const float*)d_in[7];
    const float* Wh  = (const float*)d_in[8];
    const float* bh  = (const float*)d_in[9];
    const float* Wm  = (const float*)d_in[10];
    const float* bm  = (const float*)d_in[11];

    float* out1 = (float*)d_out;                   // [N,3]
    float* out2 = out1 + (size_t)N_NODES * 3;      // [N,8]

    char* ws = (char*)d_ws;
    int*   deg      = (int*)(ws);                          // 100000 ints
    int*   rowstart = (int*)(ws + (512 << 10));            // 100001 ints
    int*   cursor   = (int*)(ws + (1024 << 10));           // 100000 ints
    int*   bsum     = (int*)(ws + (1408 << 10));           // 98 ints
    int*   boff     = (int*)(ws + (1472 << 10));           // 98 ints
    int*   srcs     = (int*)(ws + (1536 << 10));           // 1.6M ints -> ends 7936K
    unsigned short* xh  = (unsigned short*)(ws + (8192 << 10));   // 6.4M bf16 (12.8MB)
    float* h1       = (float*)(ws + (21504 << 10));        // 12.8M floats (51.2MB)
    unsigned short* h1h = (unsigned short*)(ws + (73728 << 10)); // 12.8M bf16 (25.6MB)

    const int NSCAN = (N_NODES + 1023) / 1024;             // 98

    k_cast_x<<<6250, 256, 0, stream>>>(x, xh);
    hipMemsetAsync(deg, 0, N_NODES * sizeof(int), stream);
    k_hist<<<6250, 256, 0, stream>>>(dst, deg);
    k_part_scan<<<NSCAN, 1024, 0, stream>>>(deg, rowstart, bsum);
    k_scan_bsum<<<1, 128, 0, stream>>>(bsum, boff, rowstart, NSCAN);
    k_add_off<<<NSCAN, 1024, 0, stream>>>(boff, rowstart);
    hipMemcpyAsync(cursor, rowstart, N_NODES * sizeof(int), hipMemcpyDeviceToDevice, stream);
    k_fill<<<6250, 256, 0, stream>>>(src, dst, cursor, srcs);

    k_layer1<<<3125, 256, 0, stream>>>(x, xh, rowstart, srcs, Wl1, Wr1, b1, h1, h1h);
    k_layer2<<<3125, 256, 0, stream>>>(h1, (const unsigned int*)h1h, rowstart, srcs,
                                       Wl2, Wr2, b2, Wh, bh, Wm, bm, out1, out2);
}